// Round 3
// baseline (1837.930 us; speedup 1.0000x reference)
//
#include <hip/hip_runtime.h>
#include <math.h>

typedef __attribute__((ext_vector_type(4))) float    f32x4;
typedef __attribute__((ext_vector_type(4))) _Float16 f16x4;
typedef __attribute__((ext_vector_type(8))) _Float16 f16x8;

constexpr int Bc  = 4;
constexpr int Tc  = 2048;
constexpr int Vc  = 2048;
constexpr int Dc  = 512;
constexpr int Hc  = 8;
constexpr int HDc = 64;
constexpr int Lc  = 4;

// ---------------------------------------------------------------------------
// f16-MFMA GEMM, NT layout: acc = scale * A[M,K] @ W[N,K]^T
// fp32 A and W in, f16 MFMA compute, fp32 accumulate. Epilogue by CMODE:
//   CMODE 0: fp32 flat C[M,N] (+ pos add if pos != nullptr)
//   CMODE 2: f16 head-separated  C[(b*H+h)*T + t][64]      (Q, K)
//   CMODE 3: f16 head-sep transposed C[(b*H+h)*64 + d][T]  (V^T), f16x4 stores
// BM=BN=128, BK=32, 256 threads = 4 waves (2x2), each wave 64x64 out.
// ---------------------------------------------------------------------------
template<int CMODE>
__global__ __launch_bounds__(256) void gemm_nt_f16(
    const float* __restrict__ A, const float* __restrict__ W,
    void* __restrict__ Cout, const float* __restrict__ pos,
    int K, int N, float scale)
{
    __shared__ _Float16 As[128][40];
    __shared__ _Float16 Bs[128][40];

    const int tid = threadIdx.x;
    const int w   = tid >> 6, l = tid & 63;
    const int li  = l & 15, lg = l >> 4;
    const int wm  = w >> 1, wn = w & 1;
    const int m0  = blockIdx.y * 128, n0 = blockIdx.x * 128;

    f32x4 acc[4][4];
#pragma unroll
    for (int i = 0; i < 4; ++i)
#pragma unroll
        for (int j = 0; j < 4; ++j) acc[i][j] = (f32x4){0.f, 0.f, 0.f, 0.f};

    for (int kt = 0; kt < K; kt += 32) {
#pragma unroll
        for (int i = 0; i < 4; ++i) {
            const int g   = i * 256 + tid;
            const int row = g >> 3;
            const int c4  = (g & 7) * 4;
            float4 av = *(const float4*)(A + (size_t)(m0 + row) * K + kt + c4);
            float4 wv = *(const float4*)(W + (size_t)(n0 + row) * K + kt + c4);
            f16x4 ah = {(_Float16)av.x, (_Float16)av.y, (_Float16)av.z, (_Float16)av.w};
            f16x4 wh = {(_Float16)wv.x, (_Float16)wv.y, (_Float16)wv.z, (_Float16)wv.w};
            *(f16x4*)&As[row][c4] = ah;
            *(f16x4*)&Bs[row][c4] = wh;
        }
        __syncthreads();

        f16x8 af[4], bf[4];
#pragma unroll
        for (int mb = 0; mb < 4; ++mb)
            af[mb] = *(const f16x8*)&As[wm * 64 + mb * 16 + li][lg * 8];
#pragma unroll
        for (int nb = 0; nb < 4; ++nb)
            bf[nb] = *(const f16x8*)&Bs[wn * 64 + nb * 16 + li][lg * 8];

#pragma unroll
        for (int mb = 0; mb < 4; ++mb)
#pragma unroll
            for (int nb = 0; nb < 4; ++nb)
                acc[mb][nb] = __builtin_amdgcn_mfma_f32_16x16x32_f16(
                    af[mb], bf[nb], acc[mb][nb], 0, 0, 0);
        __syncthreads();
    }

    // Epilogue. C/D layout: col = lane&15, row = (lane>>4)*4 + reg.
#pragma unroll
    for (int mb = 0; mb < 4; ++mb) {
#pragma unroll
        for (int nb = 0; nb < 4; ++nb) {
            const int mbase = m0 + wm * 64 + mb * 16 + lg * 4;
            const int ncol  = n0 + wn * 64 + nb * 16 + li;
            if (CMODE == 3) {
                // V^T: rows m are t-contiguous -> one f16x4 store
                const int bb2 = mbase >> 11, t0 = mbase & (Tc - 1);
                const int hh2 = ncol >> 6,  dd = ncol & (HDc - 1);
                f16x4 vv;
#pragma unroll
                for (int r = 0; r < 4; ++r) vv[r] = (_Float16)(acc[mb][nb][r] * scale);
                _Float16* C16 = (_Float16*)Cout;
                *(f16x4*)&C16[(((size_t)bb2 * Hc + hh2) * HDc + dd) * Tc + t0] = vv;
            } else {
#pragma unroll
                for (int r = 0; r < 4; ++r) {
                    const int m = mbase + r;
                    float val = acc[mb][nb][r] * scale;
                    if (CMODE == 0) {
                        if (pos) val += pos[(size_t)(m & (Tc - 1)) * Dc + ncol];
                        ((float*)Cout)[(size_t)m * N + ncol] = val;
                    } else {  // CMODE 2: head-separated f16
                        const int bb2 = m >> 11, t = m & (Tc - 1);
                        const int hh2 = ncol >> 6, dd = ncol & (HDc - 1);
                        ((_Float16*)Cout)[(((size_t)bb2 * Hc + hh2) * Tc + t) * HDc + dd] =
                            (_Float16)val;
                    }
                }
            }
        }
    }
}

// ---------------------------------------------------------------------------
// MFMA flash attention. Inputs f16: Q,K [BH][T][64]; Vt [BH][64][T].
// Output O fp32 [B][T][D] (flat, head-interleaved cols).
// 4 waves/block, each wave 16 q-rows; KVBLK=32 per iteration.
// S^T = mfma_16x16x32(A=K, B=Q); PV: O^T += mfma_16x16x16(A=Vt, B=P^T).
// ---------------------------------------------------------------------------
__global__ __launch_bounds__(256) void attn_mfma(
    const _Float16* __restrict__ Qh, const _Float16* __restrict__ Kh,
    const _Float16* __restrict__ Vt, float* __restrict__ o)
{
    const int bid = blockIdx.x;
    const int qt  = bid & 31;
    const int bh  = bid >> 5;
    const int hh  = bh & (Hc - 1);
    const int bb  = bh >> 3;
    const int w   = threadIdx.x >> 6;
    const int l   = threadIdx.x & 63;
    const int li  = l & 15, lg = l >> 4;
    const int q0  = qt * 64 + w * 16;

    const _Float16* Qb = Qh + (size_t)bh * Tc * HDc;
    const _Float16* Kb = Kh + (size_t)bh * Tc * HDc;
    const _Float16* Vb = Vt + (size_t)bh * HDc * Tc;

    // Q B-frags: lane holds Q[q0+li][fi*32 + lg*8 + j]
    f16x8 qf[2];
#pragma unroll
    for (int fi = 0; fi < 2; ++fi)
        qf[fi] = *(const f16x8*)&Qb[(size_t)(q0 + li) * HDc + fi * 32 + lg * 8];

    f32x4 oacc[4];
#pragma unroll
    for (int dt = 0; dt < 4; ++dt) oacc[dt] = (f32x4){0.f, 0.f, 0.f, 0.f};
    float mrun = -1e30f, lrun = 0.f;

    for (int kt = 0; kt < Tc / 32; ++kt) {
        // ---- S^T tiles (2 x 16k x 16q), contraction over d=64 via 2 mfma each
        f32x4 s[2];
#pragma unroll
        for (int t = 0; t < 2; ++t) {
            s[t] = (f32x4){0.f, 0.f, 0.f, 0.f};
            const _Float16* kr = Kb + (size_t)(kt * 32 + t * 16 + li) * HDc + lg * 8;
#pragma unroll
            for (int fi = 0; fi < 2; ++fi) {
                f16x8 kf = *(const f16x8*)(kr + fi * 32);
                s[t] = __builtin_amdgcn_mfma_f32_16x16x32_f16(kf, qf[fi], s[t], 0, 0, 0);
            }
        }

        float sv[8];
#pragma unroll
        for (int t = 0; t < 2; ++t)
#pragma unroll
            for (int r = 0; r < 4; ++r) sv[t * 4 + r] = s[t][r] * 0.125f;

        // ---- online softmax (reduce over k: lanes l, l^16, l^32 share q)
        float mt = sv[0];
#pragma unroll
        for (int i = 1; i < 8; ++i) mt = fmaxf(mt, sv[i]);
        mt = fmaxf(mt, __shfl_xor(mt, 16));
        mt = fmaxf(mt, __shfl_xor(mt, 32));
        const float mnew = fmaxf(mrun, mt);
        const float fsc  = __expf(mrun - mnew);

        float p[8], ps = 0.f;
#pragma unroll
        for (int i = 0; i < 8; ++i) { p[i] = __expf(sv[i] - mnew); ps += p[i]; }
        ps += __shfl_xor(ps, 16);
        ps += __shfl_xor(ps, 32);
        lrun = lrun * fsc + ps;
        mrun = mnew;

        f16x4 pf[2];
#pragma unroll
        for (int t = 0; t < 2; ++t)
            pf[t] = (f16x4){(_Float16)p[t * 4 + 0], (_Float16)p[t * 4 + 1],
                            (_Float16)p[t * 4 + 2], (_Float16)p[t * 4 + 3]};

        // ---- O^T rescale + PV (A = Vt contiguous f16x4, B = pf in-layout)
#pragma unroll
        for (int dt = 0; dt < 4; ++dt) oacc[dt] *= fsc;
#pragma unroll
        for (int dt = 0; dt < 4; ++dt) {
            const _Float16* vr = Vb + (size_t)(dt * 16 + li) * Tc + kt * 32 + lg * 4;
#pragma unroll
            for (int t = 0; t < 2; ++t) {
                f16x4 vf = *(const f16x4*)(vr + t * 16);
                oacc[dt] = __builtin_amdgcn_mfma_f32_16x16x16f16(vf, pf[t], oacc[dt], 0, 0, 0);
            }
        }
    }

    // ---- write O: lane holds q = li, d = dt*16 + lg*4 + r (r contiguous)
    const float inv = 1.f / lrun;
    float* op = o + ((size_t)(bb * Tc + q0 + li) * Dc + hh * HDc + lg * 4);
#pragma unroll
    for (int dt = 0; dt < 4; ++dt) {
        f32x4 rv = oacc[dt] * inv;
        *(f32x4*)(op + dt * 16) = rv;
    }
}

// ---------------------------------------------------------------------------
__global__ __launch_bounds__(256) void readout_k(
    const float* __restrict__ h, const float* __restrict__ ro,
    float* __restrict__ out, float scale)
{
    const int idx = blockIdx.x * 256 + threadIdx.x;
    const int vv  = idx & (Vc - 1);
    const int bb  = idx >> 11;
    const float* hp = h + (size_t)(bb * Tc + (Tc - 1)) * Dc;
    const float* rp = ro + (size_t)vv * Dc;
    float ax = 0.f, ay = 0.f, az = 0.f, aw = 0.f;
#pragma unroll 8
    for (int i = 0; i < Dc / 4; ++i) {
        float4 hv = *(const float4*)(hp + i * 4);
        float4 rv = *(const float4*)(rp + i * 4);
        ax = fmaf(hv.x, rv.x, ax);
        ay = fmaf(hv.y, rv.y, ay);
        az = fmaf(hv.z, rv.z, az);
        aw = fmaf(hv.w, rv.w, aw);
    }
    out[idx] = ((ax + ay) + (az + aw)) * scale;
}

// ---------------------------------------------------------------------------
extern "C" void kernel_launch(void* const* d_in, const int* in_sizes, int n_in,
                              void* d_out, int out_size, void* d_ws, size_t ws_size,
                              hipStream_t stream)
{
    const float* x    = (const float*)d_in[0];
    const float* temb = (const float*)d_in[1];
    const float* pemb = (const float*)d_in[2];
    const float* Wk   = (const float*)d_in[3];
    const float* Wq   = (const float*)d_in[4];
    const float* Wv   = (const float*)d_in[5];
    const float* Wp   = (const float*)d_in[6];
    const float* ro   = (const float*)d_in[7];
    float* out = (float*)d_out;

    const size_t SZ = (size_t)Bc * Tc * Dc;   // 4M elements
    float* ws = (float*)d_ws;
    float*     hbuf = ws;                     // fp32 h         (16 MB)
    float*     obuf = ws + SZ;                // fp32 attn out  (16 MB)
    _Float16*  qh   = (_Float16*)(ws + 2 * SZ);        // f16 (8 MB)
    _Float16*  kh   = qh + SZ;                          // f16 (8 MB)
    _Float16*  vt   = kh + SZ;                          // f16 (8 MB)

    const float s_emb  = 1.0f / sqrtf((float)Vc);
    const float s_proj = 1.0f / sqrtf((float)Dc);

    const dim3 gemmGrid(Dc / 128, (Bc * Tc) / 128);   // (4, 64)

    gemm_nt_f16<0><<<gemmGrid, 256, 0, stream>>>(x, temb, hbuf, pemb, Vc, Dc, s_emb);

    for (int lyr = 0; lyr < Lc; ++lyr) {
        const float* wq = Wq + (size_t)lyr * Dc * Dc;
        const float* wk = Wk + (size_t)lyr * Dc * Dc;
        const float* wv = Wv + (size_t)lyr * Dc * Dc;
        const float* wp = Wp + (size_t)lyr * Dc * Dc;

        gemm_nt_f16<2><<<gemmGrid, 256, 0, stream>>>(hbuf, wq, qh, nullptr, Dc, Dc, s_proj);
        gemm_nt_f16<2><<<gemmGrid, 256, 0, stream>>>(hbuf, wk, kh, nullptr, Dc, Dc, s_proj);
        gemm_nt_f16<3><<<gemmGrid, 256, 0, stream>>>(hbuf, wv, vt, nullptr, Dc, Dc, s_proj);

        attn_mfma<<<Bc * Hc * (Tc / 64), 256, 0, stream>>>(qh, kh, vt, obuf);

        gemm_nt_f16<0><<<gemmGrid, 256, 0, stream>>>(obuf, wp, hbuf, nullptr, Dc, Dc, s_proj);
    }

    readout_k<<<(Bc * Vc) / 256, 256, 0, stream>>>(hbuf, ro, out, s_proj);
}